// Round 1
// baseline (109.577 us; speedup 1.0000x reference)
//
#include <hip/hip_runtime.h>
#include <math.h>

#define N_  2
#define C_  128
#define H_  128
#define W_  128
#define G_  4
#define GC_ 32
#define P_  9
#define O_  72
#define WT  32      // pixels per block (along w)
#define X1S 129     // LDS stride for x1/out tile (conflict-free)
#define OFS 73      // LDS stride for per-pixel offsets

__global__ __launch_bounds__(256)
void dcn_fused(const float* __restrict__ inp,   // [N,C,H,W]
               const float* __restrict__ xin,   // [N,H,W,C]
               const float* __restrict__ dww,   // [3,3,1,C] HWIO
               const float* __restrict__ dwb,   // [C]
               const float* __restrict__ lng,   // [C]
               const float* __restrict__ lnb,   // [C]
               const float* __restrict__ offw,  // [72,C]
               const float* __restrict__ offb,  // [72]
               float* __restrict__ out)         // [N,C,H,W]
{
    __shared__ float tile[WT * X1S];        // x1 (phases A), reused as out tile (phase B/C)
    __shared__ float offs[WT * OFS];        // per-pixel 72 offsets
    __shared__ float red1[8 * WT];
    __shared__ float red2[8 * WT];

    const int t   = threadIdx.x;
    const int bid = blockIdx.x;
    const int wt  = bid & 3;                // W/WT = 4
    const int h   = (bid >> 2) & (H_ - 1);
    const int n   = bid >> 9;               // / (4*128)
    const int w0  = wt * WT;

    // ---------- A1: depthwise 3x3 conv (+bias), per-pixel LN partial stats ----------
    {
        const int w = t & 31;
        const int q = t >> 5;                // 0..7, 16 channels each
        float s1 = 0.f, s2 = 0.f;
        const int wcb = w0 + w - 1;
        #pragma unroll
        for (int i = 0; i < 16; ++i) {
            const int c = q * 16 + i;
            float acc = dwb[c];
            #pragma unroll
            for (int r = 0; r < 3; ++r) {
                const int hr = h - 1 + r;
                const bool rv = (hr >= 0) && (hr < H_);
                const float* row = inp + (((size_t)n * C_ + c) * H_ + hr) * W_;
                #pragma unroll
                for (int s = 0; s < 3; ++s) {
                    const int wc = wcb + s;
                    const float v = (rv && wc >= 0 && wc < W_) ? row[wc] : 0.f;
                    acc = fmaf(v, dww[(r * 3 + s) * C_ + c], acc);
                }
            }
            tile[w * X1S + c] = acc;
            s1 += acc;
            s2 = fmaf(acc, acc, s2);
        }
        red1[q * WT + w] = s1;
        red2[q * WT + w] = s2;
    }
    __syncthreads();

    // ---------- A2: LayerNorm + exact GELU (in place) ----------
    {
        const int w = t & 31;
        const int q = t >> 5;
        float s1 = 0.f, s2 = 0.f;
        #pragma unroll
        for (int j = 0; j < 8; ++j) { s1 += red1[j * WT + w]; s2 += red2[j * WT + w]; }
        const float mean = s1 * (1.f / 128.f);
        const float var  = s2 * (1.f / 128.f) - mean * mean;
        const float rstd = rsqrtf(var + 1e-6f);
        #pragma unroll
        for (int i = 0; i < 16; ++i) {
            const int c = q * 16 + i;
            float v = tile[w * X1S + c];
            v = (v - mean) * rstd * lng[c] + lnb[c];
            v = 0.5f * v * (1.f + erff(v * 0.70710678118654752440f));  // exact gelu
            tile[w * X1S + c] = v;
        }
    }
    __syncthreads();

    // ---------- A3: offset linear  off[o] = sum_c x1[c]*W[o,c] + b[o] ----------
    {
        const int w = t & 31;
        const int s = t >> 5;                // 9 outputs per thread
        float acc[9];
        #pragma unroll
        for (int o = 0; o < 9; ++o) acc[o] = offb[s * 9 + o];
        #pragma unroll 1
        for (int cb = 0; cb < C_; cb += 8) {
            float xv[8];
            #pragma unroll
            for (int k = 0; k < 8; ++k) xv[k] = tile[w * X1S + cb + k];
            #pragma unroll
            for (int o = 0; o < 9; ++o) {
                const float4* wp = reinterpret_cast<const float4*>(&offw[(s * 9 + o) * C_ + cb]);
                const float4 wa = wp[0];
                const float4 wb = wp[1];
                acc[o] = fmaf(xv[0], wa.x, acc[o]);
                acc[o] = fmaf(xv[1], wa.y, acc[o]);
                acc[o] = fmaf(xv[2], wa.z, acc[o]);
                acc[o] = fmaf(xv[3], wa.w, acc[o]);
                acc[o] = fmaf(xv[4], wb.x, acc[o]);
                acc[o] = fmaf(xv[5], wb.y, acc[o]);
                acc[o] = fmaf(xv[6], wb.z, acc[o]);
                acc[o] = fmaf(xv[7], wb.w, acc[o]);
            }
        }
        #pragma unroll
        for (int o = 0; o < 9; ++o) offs[w * OFS + s * 9 + o] = acc[o];
    }
    __syncthreads();

    // ---------- B: DCNv3 bilinear sampling ----------
    // iy = h + (p%3) + off_y ; ix = w + (p/3) + off_x   (padded coords, pad=1)
    // value nonzero iff 1<=iy<=H && 1<=ix<=W  -> read xin[iy-1][ix-1]
    {
        const int cl   = t & 31;
        const int slot = t >> 5;             // 8 slots
        const int g    = slot & 3;
        const float* xg = xin + (size_t)n * H_ * W_ * C_ + g * GC_ + cl;
        #pragma unroll 1
        for (int it = 0; it < 16; ++it) {
            const int pair = it * 8 + slot;  // 0..127 distinct
            const int pix  = pair >> 2;      // 0..31
            const float* op = &offs[pix * OFS + g * 18];
            const float fyb = (float)h;
            const float fxb = (float)(w0 + pix);
            float acc = 0.f;
            #pragma unroll
            for (int p = 0; p < P_; ++p) {
                const float ox = op[2 * p];
                const float oy = op[2 * p + 1];
                const float fy = fyb + (float)(p % 3) + oy;
                const float fx = fxb + (float)(p / 3) + ox;
                const float y0f = floorf(fy);
                const float x0f = floorf(fx);
                const float wy = fy - y0f;
                const float wx = fx - x0f;
                const int y0 = (int)y0f;
                const int x0 = (int)x0f;

                float v00 = 0.f, v01 = 0.f, v10 = 0.f, v11 = 0.f;
                if (y0 >= 1 && y0 <= H_) {
                    const float* rr = xg + (size_t)(y0 - 1) * W_ * C_;
                    if (x0 >= 1 && x0 <= W_)         v00 = rr[(size_t)(x0 - 1) * C_];
                    if (x0 + 1 >= 1 && x0 + 1 <= W_) v01 = rr[(size_t)x0 * C_];
                }
                if (y0 + 1 >= 1 && y0 + 1 <= H_) {
                    const float* rr = xg + (size_t)y0 * W_ * C_;
                    if (x0 >= 1 && x0 <= W_)         v10 = rr[(size_t)(x0 - 1) * C_];
                    if (x0 + 1 >= 1 && x0 + 1 <= W_) v11 = rr[(size_t)x0 * C_];
                }
                acc += (1.f - wy) * ((1.f - wx) * v00 + wx * v01)
                     +         wy * ((1.f - wx) * v10 + wx * v11);
            }
            tile[pix * X1S + g * GC_ + cl] = acc;   // reuse tile as out staging
        }
    }
    __syncthreads();

    // ---------- C: coalesced NCHW write ----------
    {
        const int pix = t & 31;
        const int cq  = t >> 5;
        #pragma unroll
        for (int i = 0; i < 16; ++i) {
            const int c = cq * 16 + i;
            out[(((size_t)n * C_ + c) * H_ + h) * W_ + w0 + pix] = tile[pix * X1S + c];
        }
    }
}

extern "C" void kernel_launch(void* const* d_in, const int* in_sizes, int n_in,
                              void* d_out, int out_size, void* d_ws, size_t ws_size,
                              hipStream_t stream) {
    const float* inp  = (const float*)d_in[0];
    const float* xin  = (const float*)d_in[1];
    const float* dww  = (const float*)d_in[2];
    const float* dwb  = (const float*)d_in[3];
    const float* lng  = (const float*)d_in[4];
    const float* lnb  = (const float*)d_in[5];
    const float* offw = (const float*)d_in[6];
    const float* offb = (const float*)d_in[7];
    float* outp = (float*)d_out;

    const int blocks = N_ * H_ * (W_ / WT);   // 1024
    dcn_fused<<<dim3(blocks), dim3(256), 0, stream>>>(
        inp, xin, dww, dwb, lng, lnb, offw, offb, outp);
}